// Round 4
// baseline (457.920 us; speedup 1.0000x reference)
//
#include <hip/hip_runtime.h>
#include <math.h>

#define NROWS 65536
#define CDIM 512
#define MDIM 640
#define VDIM 320
#define DDIM 128
#define OUTN (NROWS * 256)
#define NREP 32
#define TAU1 0.30f
#define TAU2 0.01f
#define Q1CAP 32768
#define Q2CAP 8192

typedef _Float16 half8 __attribute__((ext_vector_type(8)));
typedef float f32x4 __attribute__((ext_vector_type(4)));

// async global->LDS, 16B per lane (dest must be wave-uniform base + lane*16)
#define GLD16(gp, lp)                                                       \
  __builtin_amdgcn_global_load_lds(                                         \
      (const __attribute__((address_space(1))) void*)(gp),                  \
      (__attribute__((address_space(3))) void*)(lp), 16, 0, 0)

#define SCHED_FENCE() __builtin_amdgcn_sched_barrier(0)

// ---- ws layout (byte offsets) ----
#define WPK_HI_OFF 0                         // 327680 f16 = 655360 B
#define WPK_LO_OFF 655360
#define KIDX_OFF   1310720                   // 65536*2 int
#define Q1G0_OFF   1835008                   // Q1CAP int
#define Q1G1_OFF   1966080
#define Q2_OFF     2097152                   // Q2CAP int
#define CNT_OFF    2129920                   // qc0,qc1,qc2 (+pad 256)
#define AVGP_OFF   2130176                   // NREP*640 f32
#define HIST_OFF   (AVGP_OFF + NREP * MDIM * 4)
#define WS_NEEDED  (HIST_OFF + MDIM * 4)     // 2214656 (same as proven R3)
#define ZLEN_F     ((WS_NEEDED - CNT_OFF) / 4)   // 21184 floats
#define ZBLOCKS    ((ZLEN_F + 255) / 256)        // 83

// ---- prep: pack W into MFMA B-fragment order (hi/lo) + zero counters ----
__global__ __launch_bounds__(256) void prep_kernel(
    const float* __restrict__ W, _Float16* __restrict__ ph,
    _Float16* __restrict__ pl, float* __restrict__ zbase) {
  int bid = blockIdx.x;
  int t = threadIdx.x;
  if (bid < 160) {
    int idx = bid * 256 + t;  // 40960 lane-slots
    int lane = idx & 63;
    int rest = idx >> 6;      // (ks*2+g)*20+nt  == ks*40 + g*20 + nt
    int nt = rest % 20;
    int gks = rest / 20;
    int g = gks & 1, ks = gks >> 1;
    int col = g * VDIM + nt * 16 + (lane & 15);
    int kbase = ks * 32 + (lane >> 4) * 8;
    _Float16 hh[8], ll[8];
#pragma unroll
    for (int j = 0; j < 8; ++j) {
      float w = W[(size_t)(kbase + j) * MDIM + col];
      _Float16 h = (_Float16)w;
      hh[j] = h;
      ll[j] = (_Float16)(w - (float)h);
    }
    *(half8*)&ph[(size_t)idx * 8] = *(half8*)hh;
    *(half8*)&pl[(size_t)idx * 8] = *(half8*)ll;
  } else {
    int i = (bid - 160) * 256 + t;
    if (i < ZLEN_F) zbase[i] = 0.f;
  }
}

// ---- tier-1: f16-hi GEMM + argmax/top2 + softmax + fused gather + hist ----
// 512 threads = 8 waves; wave w: g = w&1, rows rbase=(w>>1)*32 (2 mt of 16).
// W staged via global_load_lds into 80KB double buffer. Counted-vmcnt raw
// barrier discipline (T3/T4): per ks, issue stage(ks+1), compute on buf(ks),
// then s_waitcnt vmcnt(4) (= #A-prefetch loads; the 5 older GLD16 retire
// in-order) + raw s_barrier. A-loads never block the barrier.
__global__ __launch_bounds__(512, 2) void t1_gemm_kernel(
    const float* __restrict__ x, const float* __restrict__ bias,
    const _Float16* __restrict__ wpk_hi, const float* __restrict__ cb,
    float* __restrict__ out, int* __restrict__ k_idx,
    int* __restrict__ q1g0, int* __restrict__ q1g1, int* __restrict__ qc,
    float* __restrict__ ws_avgp, float* __restrict__ hist) {
  __shared__ alignas(16) _Float16 wlds[2][20480];  // 2 x 40KB = 80KB exactly

  const int t = threadIdx.x;
  const int wave = t >> 6, lane = t & 63;
  const int quad = lane >> 4, l15 = lane & 15;
  const int row0 = blockIdx.x * 128;
  const int g = wave & 1;
  const int rbase = (wave >> 1) * 32;

  f32x4 acc[2][20];
#pragma unroll
  for (int mt = 0; mt < 2; ++mt)
#pragma unroll
    for (int nt = 0; nt < 20; ++nt) acc[mt][nt] = (f32x4)0.f;

  const float4* wsrc4 = (const float4*)wpk_hi;  // frag-packed, ks-major
  // A source: row = row0 + rbase + mt*16 + l15, k = ks*32 + quad*8 .. +7
  const float4* xA0 =
      (const float4*)x + (size_t)(row0 + rbase + l15) * 128 + quad * 2;
  const float4* xA1 = xA0 + (size_t)16 * 128;  // mt=1: +16 rows

  // prologue: stage ks=0 into buf0 (5 GLD16), then A(0) prefetch (4 loads)
#pragma unroll
  for (int j = 0; j < 5; ++j)
    GLD16(wsrc4 + j * 512 + t, &wlds[0][(size_t)(j * 512 + t) * 8]);
  SCHED_FENCE();
  float4 a00 = xA0[0], a01 = xA0[1];
  float4 a10 = xA1[0], a11 = xA1[1];
  SCHED_FENCE();
  asm volatile("s_waitcnt vmcnt(4)" ::: "memory");  // GLD16(0) retired
  __builtin_amdgcn_s_barrier();

#pragma unroll 1
  for (int ks = 0; ks < 16; ++ks) {
    const int cur = ks & 1;
    // issue next W stage into the other buffer (stays in flight across
    // the compute phase AND the end-of-iteration barrier wait of others)
    if (ks < 15) {
      const float4* wnext = wsrc4 + (size_t)(ks + 1) * 2560;
#pragma unroll
      for (int j = 0; j < 5; ++j)
        GLD16(wnext + j * 512 + t,
              &wlds[cur ^ 1][(size_t)(j * 512 + t) * 8]);
    }
    SCHED_FENCE();
    // convert A(ks) regs -> f16 fragments (compiler emits minimal per-wave
    // vmcnt for a00..a11; does NOT drain the GLD16s just issued)
    half8 a0h, a1h;
    {
      float va[8] = {a00.x, a00.y, a00.z, a00.w, a01.x, a01.y, a01.z, a01.w};
      float vb[8] = {a10.x, a10.y, a10.z, a10.w, a11.x, a11.y, a11.z, a11.w};
#pragma unroll
      for (int j = 0; j < 8; ++j) {
        a0h[j] = (_Float16)va[j];
        a1h[j] = (_Float16)vb[j];
      }
    }
    // prefetch A(ks+1) (newest 4 VMEM ops)
    if (ks < 15) {
      a00 = xA0[(ks + 1) * 8];
      a01 = xA0[(ks + 1) * 8 + 1];
      a10 = xA1[(ks + 1) * 8];
      a11 = xA1[(ks + 1) * 8 + 1];
    }
    SCHED_FENCE();
#pragma unroll
    for (int nt = 0; nt < 20; ++nt) {
      half8 bb = *(const half8*)&wlds[cur][(g * 20 + nt) * 512 + lane * 8];
      acc[0][nt] = __builtin_amdgcn_mfma_f32_16x16x32_f16(a0h, bb, acc[0][nt], 0, 0, 0);
      acc[1][nt] = __builtin_amdgcn_mfma_f32_16x16x32_f16(a1h, bb, acc[1][nt], 0, 0, 0);
    }
    SCHED_FENCE();
    // counted wait: retire the 5 GLD16(ks+1) (oldest); leave A(ks+1) in flight
    if (ks < 15)
      asm volatile("s_waitcnt vmcnt(4)" ::: "memory");
    else
      asm volatile("s_waitcnt vmcnt(0)" ::: "memory");
    __builtin_amdgcn_s_barrier();  // all waves' stage(ks+1) now visible
  }

  // K-loop done; wlds is dead -> reuse first 1KB as rowk
  int(*rowk)[2] = (int(*)[2]) & wlds[0][0];

  // bias
#pragma unroll
  for (int nt = 0; nt < 20; ++nt) {
    float bb = bias[g * VDIM + nt * 16 + l15];
#pragma unroll
    for (int mt = 0; mt < 2; ++mt) {
      acc[mt][nt][0] += bb; acc[mt][nt][1] += bb;
      acc[mt][nt][2] += bb; acc[mt][nt][3] += bb;
    }
  }

  // ---- epilogue: top2/argmax + softmax partials + provisional k ----
  int* qg = (g == 0) ? q1g0 : q1g1;
  float pp[20];
#pragma unroll
  for (int nt = 0; nt < 20; ++nt) pp[nt] = 0.f;

#pragma unroll
  for (int mt = 0; mt < 2; ++mt) {
#pragma unroll
    for (int reg = 0; reg < 4; ++reg) {
      float m1 = -1e30f, m2 = -1e30f;
      int i1 = 0;
#pragma unroll
      for (int nt = 0; nt < 20; ++nt) {
        float v = acc[mt][nt][reg];
        int ci = nt * 16 + l15;
        if (v > m1) { m2 = m1; m1 = v; i1 = ci; }
        else if (v > m2) m2 = v;
      }
#pragma unroll
      for (int off = 1; off <= 8; off <<= 1) {
        float om1 = __shfl_xor(m1, off);
        int oi1 = __shfl_xor(i1, off);
        float om2 = __shfl_xor(m2, off);
        if (om1 > m1 || (om1 == m1 && oi1 < i1)) {
          m2 = fmaxf(m1, om2); m1 = om1; i1 = oi1;
        } else {
          m2 = fmaxf(m2, om1);
        }
      }
      float z = 0.f;
#pragma unroll
      for (int nt = 0; nt < 20; ++nt) z += __expf(acc[mt][nt][reg] - m1);
#pragma unroll
      for (int off = 1; off <= 8; off <<= 1) z += __shfl_xor(z, off);
      float rz = 1.f / z;
#pragma unroll
      for (int nt = 0; nt < 20; ++nt)
        pp[nt] += __expf(acc[mt][nt][reg] - m1) * rz;

      if (l15 == 0) {
        int glocal = rbase + mt * 16 + quad * 4 + reg;
        int grow = row0 + glocal;
        rowk[glocal][g] = i1;
        k_idx[grow * 2 + g] = i1;
        atomicAdd(&hist[g * VDIM + i1], 1.f);
        if (m1 - m2 < TAU1) {
          int qi = atomicAdd(&qc[g], 1);
          if (qi < Q1CAP) qg[qi] = grow;
        }
      }
    }
  }
#pragma unroll
  for (int nt = 0; nt < 20; ++nt) {
    pp[nt] += __shfl_xor(pp[nt], 16);
    pp[nt] += __shfl_xor(pp[nt], 32);
  }
  if (quad == 0) {
    float* dst = ws_avgp + (size_t)(blockIdx.x & (NREP - 1)) * MDIM + g * VDIM + l15;
#pragma unroll
    for (int nt = 0; nt < 20; ++nt) atomicAdd(dst + nt * 16, pp[nt]);
  }

  // ---- fused gather-write: out rows from rowk ----
  __syncthreads();
  const float4* cb4 = (const float4*)cb;
  float4* out4 = (float4*)out;
#pragma unroll
  for (int it = 0; it < 16; ++it) {
    int i = it * 512 + t;         // 8192 float4 slots = 128 rows * 64
    int row = i >> 6, f4 = i & 63;
    int gg = f4 >> 5, d4 = f4 & 31;
    int kk = rowk[row][gg];
    out4[(size_t)(row0 + row) * 64 + f4] = cb4[(size_t)(gg * VDIM + kk) * 32 + d4];
  }
}

// ---- tier-2: f16x3 recompute of flagged entries; fix-forward out/hist ----
// Same counted-vmcnt raw-barrier discipline as t1: 10 GLD16 (hi+lo) per ks
// into 80KB double buffer, 2 x-prefetch loads per ks; vmcnt(2) at iteration
// end retires the 10 older GLD16s, leaves x-prefetch in flight.
__global__ __launch_bounds__(256) void t2_kernel(
    const float* __restrict__ x, const float* __restrict__ bias,
    const _Float16* __restrict__ wpk_hi, const _Float16* __restrict__ wpk_lo,
    const int* __restrict__ q1g0, const int* __restrict__ q1g1,
    const int* __restrict__ qc, int* __restrict__ k_idx,
    int* __restrict__ q2, int* __restrict__ qc2,
    const float* __restrict__ cb, float* __restrict__ out,
    float* __restrict__ hist) {
  __shared__ alignas(16) _Float16 whl[2][2][10240];  // [buf][hi/lo][20KB] = 80KB
  __shared__ int sh_row[4][16];
  __shared__ int sh_k[4][16];
  const int t = threadIdx.x;
  const int wave = t >> 6, lane = t & 63;
  const int quad = lane >> 4, l15 = lane & 15;
  const float4* cb4 = (const float4*)cb;
  float4* out4 = (float4*)out;
  const float4* whi4 = (const float4*)wpk_hi;  // 1280 float4 per (ks,g) block
  const float4* wlo4 = (const float4*)wpk_lo;

  for (int g = 0; g < 2; ++g) {
    const int* queue = (g == 0) ? q1g0 : q1g1;
    int n = qc[g];
    if (n > Q1CAP) n = Q1CAP;

    for (int tbase0 = blockIdx.x * 64; tbase0 < n; tbase0 += gridDim.x * 64) {
      int tbase = tbase0 + wave * 16;
      int e = tbase + l15;
      int row = (e < n) ? queue[e] : 0;

      f32x4 acc[20];
#pragma unroll
      for (int nt = 0; nt < 20; ++nt) acc[nt] = (f32x4)0.f;

      const float4* xp = (const float4*)x + (size_t)row * 128 + quad * 2;

      // prologue: stage ks=0 (hi+lo, 10 GLD16) into buf0, prefetch x(0)
      {
        const float4* sh = whi4 + (size_t)g * 1280;   // ks=0
        const float4* sl = wlo4 + (size_t)g * 1280;
#pragma unroll
        for (int j = 0; j < 5; ++j) {
          GLD16(sh + j * 256 + t, &whl[0][0][(size_t)(j * 256 + t) * 8]);
          GLD16(sl + j * 256 + t, &whl[0][1][(size_t)(j * 256 + t) * 8]);
        }
      }
      SCHED_FENCE();
      float4 va = xp[0], vb = xp[1];
      SCHED_FENCE();
      asm volatile("s_waitcnt vmcnt(2)" ::: "memory");  // 10 GLD16 retired
      __builtin_amdgcn_s_barrier();

#pragma unroll 1
      for (int ks = 0; ks < 16; ++ks) {
        const int cur = ks & 1;
        if (ks < 15) {
          const float4* sh = whi4 + (size_t)((ks + 1) * 2 + g) * 1280;
          const float4* sl = wlo4 + (size_t)((ks + 1) * 2 + g) * 1280;
#pragma unroll
          for (int j = 0; j < 5; ++j) {
            GLD16(sh + j * 256 + t, &whl[cur ^ 1][0][(size_t)(j * 256 + t) * 8]);
            GLD16(sl + j * 256 + t, &whl[cur ^ 1][1][(size_t)(j * 256 + t) * 8]);
          }
        }
        SCHED_FENCE();
        half8 ah, al;
        {
          float vv[8] = {va.x, va.y, va.z, va.w, vb.x, vb.y, vb.z, vb.w};
#pragma unroll
          for (int j = 0; j < 8; ++j) {
            ah[j] = (_Float16)vv[j];
            al[j] = (_Float16)(vv[j] - (float)ah[j]);
          }
        }
        if (ks < 15) {
          va = xp[(ks + 1) * 8];
          vb = xp[(ks + 1) * 8 + 1];
        }
        SCHED_FENCE();
#pragma unroll
        for (int nt = 0; nt < 20; ++nt) {
          half8 bh = *(const half8*)&whl[cur][0][nt * 512 + lane * 8];
          half8 bl = *(const half8*)&whl[cur][1][nt * 512 + lane * 8];
          acc[nt] = __builtin_amdgcn_mfma_f32_16x16x32_f16(ah, bh, acc[nt], 0, 0, 0);
          acc[nt] = __builtin_amdgcn_mfma_f32_16x16x32_f16(ah, bl, acc[nt], 0, 0, 0);
          acc[nt] = __builtin_amdgcn_mfma_f32_16x16x32_f16(al, bh, acc[nt], 0, 0, 0);
        }
        SCHED_FENCE();
        if (ks < 15)
          asm volatile("s_waitcnt vmcnt(2)" ::: "memory");
        else
          asm volatile("s_waitcnt vmcnt(0)" ::: "memory");
        __builtin_amdgcn_s_barrier();
      }
      __syncthreads();  // safety: reads done before next unit re-stages buf0

#pragma unroll
      for (int reg = 0; reg < 4; ++reg) {
        float m1 = -1e30f, m2 = -1e30f;
        int i1 = 0;
#pragma unroll
        for (int nt = 0; nt < 20; ++nt) {
          float v = acc[nt][reg] + bias[g * VDIM + nt * 16 + l15];
          int ci = nt * 16 + l15;
          if (v > m1) { m2 = m1; m1 = v; i1 = ci; }
          else if (v > m2) m2 = v;
        }
#pragma unroll
        for (int off = 1; off <= 8; off <<= 1) {
          float om1 = __shfl_xor(m1, off);
          int oi1 = __shfl_xor(i1, off);
          float om2 = __shfl_xor(m2, off);
          if (om1 > m1 || (om1 == m1 && oi1 < i1)) {
            m2 = fmaxf(m1, om2); m1 = om1; i1 = oi1;
          } else {
            m2 = fmaxf(m2, om1);
          }
        }
        if (l15 == 0) {
          int ew = tbase + quad * 4 + reg;
          int ent = quad * 4 + reg;
          if (ew < n) {
            int rw = queue[ew];
            int kold = k_idx[rw * 2 + g];
            if (i1 != kold) {
              atomicAdd(&hist[g * VDIM + kold], -1.f);
              atomicAdd(&hist[g * VDIM + i1], 1.f);
              k_idx[rw * 2 + g] = i1;
            }
            sh_row[wave][ent] = rw;
            sh_k[wave][ent] = i1;
            if (m1 - m2 < TAU2) {
              int qi = atomicAdd(qc2, 1);
              if (qi < Q2CAP) q2[qi] = rw * 2 + g;
            }
          } else {
            sh_row[wave][ent] = -1;
          }
        }
      }
      // wave-lockstep: LDS writes above visible to this wave's lanes
#pragma unroll
      for (int j = 0; j < 8; ++j) {
        int slot = j * 64 + lane;     // 512 slots = 16 ents * 32 float4
        int ent = slot >> 5, d4 = slot & 31;
        int rr = sh_row[wave][ent];
        if (rr >= 0) {
          int kk = sh_k[wave][ent];
          out4[(size_t)rr * 64 + g * 32 + d4] = cb4[(size_t)(g * VDIM + kk) * 32 + d4];
        }
      }
    }
  }
}

// ---- tier-3: exact f64 recompute; fix-forward out/hist ----
__global__ __launch_bounds__(256) void fixup_kernel(
    const float* __restrict__ x, const float* __restrict__ W,
    const float* __restrict__ bias, const int* __restrict__ queue,
    const int* __restrict__ qcount, const int* __restrict__ k_idx,
    const float* __restrict__ cb, float* __restrict__ out,
    float* __restrict__ hist) {
  __shared__ float xrow[CDIM];
  __shared__ double sval[256];
  __shared__ int sidx[256];
  __shared__ int sk3;
  const int t = threadIdx.x;
  int n = *qcount;
  if (n > Q2CAP) n = Q2CAP;
  for (int i = blockIdx.x; i < n; i += gridDim.x) {
    int e = queue[i];
    int row = e >> 1, g = e & 1;
    __syncthreads();
    xrow[t] = x[(size_t)row * CDIM + t];
    xrow[t + 256] = x[(size_t)row * CDIM + 256 + t];
    __syncthreads();
    double bv = -1e300;
    int bi = 0;
    for (int c = t; c < VDIM; c += 256) {
      const float* wp = W + g * VDIM + c;
      double a0 = 0, a1 = 0, a2 = 0, a3 = 0;
      for (int k = 0; k < CDIM; k += 4) {
        a0 = fma((double)xrow[k],     (double)wp[(size_t)k * MDIM], a0);
        a1 = fma((double)xrow[k + 1], (double)wp[(size_t)(k + 1) * MDIM], a1);
        a2 = fma((double)xrow[k + 2], (double)wp[(size_t)(k + 2) * MDIM], a2);
        a3 = fma((double)xrow[k + 3], (double)wp[(size_t)(k + 3) * MDIM], a3);
      }
      double a = ((a0 + a1) + (a2 + a3)) + (double)bias[g * VDIM + c];
      if (a > bv) { bv = a; bi = c; }
    }
    sval[t] = bv; sidx[t] = bi;
    __syncthreads();
    for (int s = 128; s > 0; s >>= 1) {
      if (t < s) {
        if (sval[t + s] > sval[t] ||
            (sval[t + s] == sval[t] && sidx[t + s] < sidx[t])) {
          sval[t] = sval[t + s]; sidx[t] = sidx[t + s];
        }
      }
      __syncthreads();
    }
    if (t == 0) {
      int k3 = sidx[0];
      int kold = k_idx[row * 2 + g];
      if (k3 != kold) {
        atomicAdd(&hist[g * VDIM + kold], -1.f);
        atomicAdd(&hist[g * VDIM + k3], 1.f);
      }
      sk3 = k3;
    }
    __syncthreads();
    if (t < 32) {
      const float4* cb4 = (const float4*)cb;
      float4* out4 = (float4*)out;
      out4[(size_t)row * 64 + g * 32 + t] = cb4[(size_t)(g * VDIM + sk3) * 32 + t];
    }
  }
}

__global__ __launch_bounds__(256) void gvq_finalize_kernel(
    const float* __restrict__ ws_avgp, const float* __restrict__ ws_hist,
    float* __restrict__ out) {
  __shared__ double red[256];
  const int t = threadIdx.x;
  double pp[2] = {0.0, 0.0}, hp[2] = {0.0, 0.0};
  for (int c = t; c < MDIM; c += 256) {
    double s = 0.0;
    for (int rep = 0; rep < NREP; ++rep) s += (double)ws_avgp[rep * MDIM + c];
    double avg = s / (double)NROWS;
    double hard = (double)ws_hist[c] / (double)NROWS;
    int g = (c < VDIM) ? 0 : 1;
    pp[g] += avg * log(avg + 1e-7);
    hp[g] += hard * log(hard + 1e-7);
  }
  double vals[4] = {pp[0], pp[1], hp[0], hp[1]};
  double res[4];
  for (int i = 0; i < 4; ++i) {
    red[t] = vals[i];
    __syncthreads();
    for (int s = 128; s > 0; s >>= 1) {
      if (t < s) red[t] += red[t + s];
      __syncthreads();
    }
    res[i] = red[0];
    __syncthreads();
  }
  if (t == 0) {
    out[OUTN]     = (float)(exp(-res[2]) + exp(-res[3]));
    out[OUTN + 1] = (float)(exp(-res[0]) + exp(-res[1]));
  }
}

// ================= fallback (round-1 verified f64 path) =================
__global__ __launch_bounds__(256) void zero_ws_kernel(float* ws, int n) {
  int i = blockIdx.x * 256 + threadIdx.x;
  if (i < n) ws[i] = 0.f;
}

__global__ __launch_bounds__(256) void fb_main_kernel(
    const float* __restrict__ x, const float* __restrict__ W,
    const float* __restrict__ b, const float* __restrict__ cb,
    float* __restrict__ out, float* __restrict__ ws_avgp,
    float* __restrict__ ws_hist) {
  __shared__ float xs[8][CDIM];
  __shared__ float lg[8][MDIM];
  __shared__ float avgp[MDIM];
  __shared__ int rowk[8][2];
  const int t = threadIdx.x;
  const int row0 = blockIdx.x * 8;
  avgp[t] = 0.f; avgp[t + 256] = 0.f;
  if (t < 128) avgp[t + 512] = 0.f;
  const float4* x4 = (const float4*)(x + (size_t)row0 * CDIM);
  float4* xs4 = (float4*)&xs[0][0];
#pragma unroll
  for (int i = 0; i < 4; ++i) xs4[t + i * 256] = x4[t + i * 256];
  __syncthreads();
  const int c0 = t, c1 = t + 256;
  const int c2 = (t < 128) ? (t + 512) : 639;
  double a0[8], a1[8], a2[8];
#pragma unroll
  for (int r = 0; r < 8; ++r) { a0[r] = 0.0; a1[r] = 0.0; a2[r] = 0.0; }
  const float* Wk = W;
  for (int k = 0; k < CDIM; ++k) {
    double w0 = (double)Wk[c0], w1 = (double)Wk[c1], w2 = (double)Wk[c2];
#pragma unroll
    for (int r = 0; r < 8; ++r) {
      double xv = (double)xs[r][k];
      a0[r] = fma(xv, w0, a0[r]);
      a1[r] = fma(xv, w1, a1[r]);
      a2[r] = fma(xv, w2, a2[r]);
    }
    Wk += MDIM;
  }
#pragma unroll
  for (int r = 0; r < 8; ++r) {
    lg[r][c0] = (float)(a0[r] + (double)b[c0]);
    lg[r][c1] = (float)(a1[r] + (double)b[c1]);
    if (t < 128) lg[r][c2] = (float)(a2[r] + (double)b[c2]);
  }
  __syncthreads();
  const int wave = t >> 6, lane = t & 63;
  for (int r = wave; r < 8; r += 4) {
    float m0 = -1e30f, m1 = -1e30f;
    int i0 = 0, i1 = VDIM;
    float e0v[5], e1v[5];
#pragma unroll
    for (int j = 0; j < 5; ++j) {
      int ca = lane + j * 64;
      float v = lg[r][ca]; e0v[j] = v;
      if (v > m0) { m0 = v; i0 = ca; }
      float v2 = lg[r][VDIM + ca]; e1v[j] = v2;
      if (v2 > m1) { m1 = v2; i1 = VDIM + ca; }
    }
#pragma unroll
    for (int off = 32; off > 0; off >>= 1) {
      float om = __shfl_xor(m0, off); int oi = __shfl_xor(i0, off);
      if (om > m0 || (om == m0 && oi < i0)) { m0 = om; i0 = oi; }
      om = __shfl_xor(m1, off); oi = __shfl_xor(i1, off);
      if (om > m1 || (om == m1 && oi < i1)) { m1 = om; i1 = oi; }
    }
    float z0 = 0.f, z1 = 0.f;
#pragma unroll
    for (int j = 0; j < 5; ++j) {
      e0v[j] = expf(e0v[j] - m0); z0 += e0v[j];
      e1v[j] = expf(e1v[j] - m1); z1 += e1v[j];
    }
#pragma unroll
    for (int off = 32; off > 0; off >>= 1) {
      z0 += __shfl_xor(z0, off); z1 += __shfl_xor(z1, off);
    }
    float r0 = 1.f / z0, r1 = 1.f / z1;
#pragma unroll
    for (int j = 0; j < 5; ++j) {
      atomicAdd(&avgp[lane + j * 64], e0v[j] * r0);
      atomicAdd(&avgp[VDIM + lane + j * 64], e1v[j] * r1);
    }
    if (lane == 0) {
      rowk[r][0] = i0; rowk[r][1] = i1 - VDIM;
      atomicAdd(&ws_hist[i0], 1.f);
      atomicAdd(&ws_hist[i1], 1.f);
    }
  }
  __syncthreads();
  const int g = t >> 7, dd = t & 127;
#pragma unroll
  for (int r = 0; r < 8; ++r) {
    int kk = rowk[r][g];
    out[(size_t)(row0 + r) * 256 + t] = cb[((size_t)(g * VDIM + kk)) * DDIM + dd];
  }
  float* dst = ws_avgp + (size_t)(blockIdx.x & 31) * MDIM;
  atomicAdd(&dst[t], avgp[t]);
  atomicAdd(&dst[t + 256], avgp[t + 256]);
  if (t < 128) atomicAdd(&dst[t + 512], avgp[t + 512]);
}

extern "C" void kernel_launch(void* const* d_in, const int* in_sizes, int n_in,
                              void* d_out, int out_size, void* d_ws, size_t ws_size,
                              hipStream_t stream) {
  const float* x  = (const float*)d_in[0];
  const float* W  = (const float*)d_in[1];
  const float* b  = (const float*)d_in[2];
  const float* cb = (const float*)d_in[3];
  float* out = (float*)d_out;
  char* ws = (char*)d_ws;

  if (ws_size >= (size_t)WS_NEEDED) {
    _Float16* wpk_hi = (_Float16*)(ws + WPK_HI_OFF);
    _Float16* wpk_lo = (_Float16*)(ws + WPK_LO_OFF);
    int* k_idx = (int*)(ws + KIDX_OFF);
    int* q1g0 = (int*)(ws + Q1G0_OFF);
    int* q1g1 = (int*)(ws + Q1G1_OFF);
    int* q2   = (int*)(ws + Q2_OFF);
    int* qc   = (int*)(ws + CNT_OFF);
    float* avgp = (float*)(ws + AVGP_OFF);
    float* hist = (float*)(ws + HIST_OFF);

    prep_kernel<<<160 + ZBLOCKS, 256, 0, stream>>>(W, wpk_hi, wpk_lo,
                                                   (float*)(ws + CNT_OFF));
    t1_gemm_kernel<<<NROWS / 128, 512, 0, stream>>>(x, b, wpk_hi, cb, out,
                                                    k_idx, q1g0, q1g1, qc,
                                                    avgp, hist);
    t2_kernel<<<128, 256, 0, stream>>>(x, b, wpk_hi, wpk_lo, q1g0, q1g1, qc,
                                       k_idx, q2, qc + 2, cb, out, hist);
    fixup_kernel<<<128, 256, 0, stream>>>(x, W, b, q2, qc + 2, k_idx, cb, out,
                                          hist);
    gvq_finalize_kernel<<<1, 256, 0, stream>>>(avgp, hist, out);
  } else {
    float* ws_avgp = (float*)ws;
    float* ws_hist = (float*)ws + NREP * MDIM;
    const int zn = NREP * MDIM + MDIM;
    zero_ws_kernel<<<(zn + 255) / 256, 256, 0, stream>>>((float*)ws, zn);
    fb_main_kernel<<<NROWS / 8, 256, 0, stream>>>(x, W, b, cb, out, ws_avgp, ws_hist);
    gvq_finalize_kernel<<<1, 256, 0, stream>>>(ws_avgp, ws_hist, out);
  }
}

// Round 5
// 438.968 us; speedup vs baseline: 1.0432x; 1.0432x over previous
//
#include <hip/hip_runtime.h>
#include <math.h>

#define NROWS 65536
#define CDIM 512
#define MDIM 640
#define VDIM 320
#define DDIM 128
#define OUTN (NROWS * 256)
#define NREP 32
#define TAU1 0.30f
#define TAU2 0.01f
#define Q1CAP 32768
#define Q2CAP 8192

typedef _Float16 half8 __attribute__((ext_vector_type(8)));
typedef float f32x4 __attribute__((ext_vector_type(4)));

// async global->LDS, 16B per lane (dest must be wave-uniform base + lane*16)
#define GLD16(gp, lp)                                                       \
  __builtin_amdgcn_global_load_lds(                                         \
      (const __attribute__((address_space(1))) void*)(gp),                  \
      (__attribute__((address_space(3))) void*)(lp), 16, 0, 0)

#define SCHED_FENCE() __builtin_amdgcn_sched_barrier(0)

// ---- ws layout (byte offsets) ----
#define WPK_HI_OFF 0                         // 327680 f16 = 655360 B
#define WPK_LO_OFF 655360
#define KIDX_OFF   1310720                   // 65536*2 int
#define Q1G0_OFF   1835008                   // Q1CAP int
#define Q1G1_OFF   1966080
#define Q2_OFF     2097152                   // Q2CAP int
#define CNT_OFF    2129920                   // qc0,qc1,qc2 (+pad 256)
#define AVGP_OFF   2130176                   // NREP*640 f32
#define HIST_OFF   (AVGP_OFF + NREP * MDIM * 4)
#define WS_NEEDED  (HIST_OFF + MDIM * 4)     // 2214656 (same as proven R3)
#define ZLEN_F     ((WS_NEEDED - CNT_OFF) / 4)   // 21184 floats
#define ZBLOCKS    ((ZLEN_F + 255) / 256)        // 83

// ---- prep: pack W into MFMA B-fragment order (hi/lo) + zero counters ----
__global__ __launch_bounds__(256) void prep_kernel(
    const float* __restrict__ W, _Float16* __restrict__ ph,
    _Float16* __restrict__ pl, float* __restrict__ zbase) {
  int bid = blockIdx.x;
  int t = threadIdx.x;
  if (bid < 160) {
    int idx = bid * 256 + t;  // 40960 lane-slots
    int lane = idx & 63;
    int rest = idx >> 6;      // (ks*2+g)*20+nt  == ks*40 + g*20 + nt
    int nt = rest % 20;
    int gks = rest / 20;
    int g = gks & 1, ks = gks >> 1;
    int col = g * VDIM + nt * 16 + (lane & 15);
    int kbase = ks * 32 + (lane >> 4) * 8;
    _Float16 hh[8], ll[8];
#pragma unroll
    for (int j = 0; j < 8; ++j) {
      float w = W[(size_t)(kbase + j) * MDIM + col];
      _Float16 h = (_Float16)w;
      hh[j] = h;
      ll[j] = (_Float16)(w - (float)h);
    }
    *(half8*)&ph[(size_t)idx * 8] = *(half8*)hh;
    *(half8*)&pl[(size_t)idx * 8] = *(half8*)ll;
  } else {
    int i = (bid - 160) * 256 + t;
    if (i < ZLEN_F) zbase[i] = 0.f;
  }
}

// ---- tier-1: f16-hi GEMM + argmax/top2 + softmax + fused gather + hist ----
// (unchanged from R4 — proven passing at 160us)
__global__ __launch_bounds__(512, 2) void t1_gemm_kernel(
    const float* __restrict__ x, const float* __restrict__ bias,
    const _Float16* __restrict__ wpk_hi, const float* __restrict__ cb,
    float* __restrict__ out, int* __restrict__ k_idx,
    int* __restrict__ q1g0, int* __restrict__ q1g1, int* __restrict__ qc,
    float* __restrict__ ws_avgp, float* __restrict__ hist) {
  __shared__ alignas(16) _Float16 wlds[2][20480];  // 2 x 40KB = 80KB exactly

  const int t = threadIdx.x;
  const int wave = t >> 6, lane = t & 63;
  const int quad = lane >> 4, l15 = lane & 15;
  const int row0 = blockIdx.x * 128;
  const int g = wave & 1;
  const int rbase = (wave >> 1) * 32;

  f32x4 acc[2][20];
#pragma unroll
  for (int mt = 0; mt < 2; ++mt)
#pragma unroll
    for (int nt = 0; nt < 20; ++nt) acc[mt][nt] = (f32x4)0.f;

  const float4* wsrc4 = (const float4*)wpk_hi;  // frag-packed, ks-major
  const float4* xA0 =
      (const float4*)x + (size_t)(row0 + rbase + l15) * 128 + quad * 2;
  const float4* xA1 = xA0 + (size_t)16 * 128;  // mt=1: +16 rows

  // prologue: stage ks=0 into buf0 (5 GLD16), then A(0) prefetch (4 loads)
#pragma unroll
  for (int j = 0; j < 5; ++j)
    GLD16(wsrc4 + j * 512 + t, &wlds[0][(size_t)(j * 512 + t) * 8]);
  SCHED_FENCE();
  float4 a00 = xA0[0], a01 = xA0[1];
  float4 a10 = xA1[0], a11 = xA1[1];
  SCHED_FENCE();
  asm volatile("s_waitcnt vmcnt(4)" ::: "memory");  // GLD16(0) retired
  __builtin_amdgcn_s_barrier();

#pragma unroll 1
  for (int ks = 0; ks < 16; ++ks) {
    const int cur = ks & 1;
    if (ks < 15) {
      const float4* wnext = wsrc4 + (size_t)(ks + 1) * 2560;
#pragma unroll
      for (int j = 0; j < 5; ++j)
        GLD16(wnext + j * 512 + t,
              &wlds[cur ^ 1][(size_t)(j * 512 + t) * 8]);
    }
    SCHED_FENCE();
    half8 a0h, a1h;
    {
      float va[8] = {a00.x, a00.y, a00.z, a00.w, a01.x, a01.y, a01.z, a01.w};
      float vb[8] = {a10.x, a10.y, a10.z, a10.w, a11.x, a11.y, a11.z, a11.w};
#pragma unroll
      for (int j = 0; j < 8; ++j) {
        a0h[j] = (_Float16)va[j];
        a1h[j] = (_Float16)vb[j];
      }
    }
    if (ks < 15) {
      a00 = xA0[(ks + 1) * 8];
      a01 = xA0[(ks + 1) * 8 + 1];
      a10 = xA1[(ks + 1) * 8];
      a11 = xA1[(ks + 1) * 8 + 1];
    }
    SCHED_FENCE();
#pragma unroll
    for (int nt = 0; nt < 20; ++nt) {
      half8 bb = *(const half8*)&wlds[cur][(g * 20 + nt) * 512 + lane * 8];
      acc[0][nt] = __builtin_amdgcn_mfma_f32_16x16x32_f16(a0h, bb, acc[0][nt], 0, 0, 0);
      acc[1][nt] = __builtin_amdgcn_mfma_f32_16x16x32_f16(a1h, bb, acc[1][nt], 0, 0, 0);
    }
    SCHED_FENCE();
    if (ks < 15)
      asm volatile("s_waitcnt vmcnt(4)" ::: "memory");
    else
      asm volatile("s_waitcnt vmcnt(0)" ::: "memory");
    __builtin_amdgcn_s_barrier();  // all waves' stage(ks+1) now visible
  }

  // K-loop done; wlds is dead -> reuse first 1KB as rowk
  int(*rowk)[2] = (int(*)[2]) & wlds[0][0];

  // bias
#pragma unroll
  for (int nt = 0; nt < 20; ++nt) {
    float bb = bias[g * VDIM + nt * 16 + l15];
#pragma unroll
    for (int mt = 0; mt < 2; ++mt) {
      acc[mt][nt][0] += bb; acc[mt][nt][1] += bb;
      acc[mt][nt][2] += bb; acc[mt][nt][3] += bb;
    }
  }

  // ---- epilogue: top2/argmax + softmax partials + provisional k ----
  int* qg = (g == 0) ? q1g0 : q1g1;
  float pp[20];
#pragma unroll
  for (int nt = 0; nt < 20; ++nt) pp[nt] = 0.f;

#pragma unroll
  for (int mt = 0; mt < 2; ++mt) {
#pragma unroll
    for (int reg = 0; reg < 4; ++reg) {
      float m1 = -1e30f, m2 = -1e30f;
      int i1 = 0;
#pragma unroll
      for (int nt = 0; nt < 20; ++nt) {
        float v = acc[mt][nt][reg];
        int ci = nt * 16 + l15;
        if (v > m1) { m2 = m1; m1 = v; i1 = ci; }
        else if (v > m2) m2 = v;
      }
#pragma unroll
      for (int off = 1; off <= 8; off <<= 1) {
        float om1 = __shfl_xor(m1, off);
        int oi1 = __shfl_xor(i1, off);
        float om2 = __shfl_xor(m2, off);
        if (om1 > m1 || (om1 == m1 && oi1 < i1)) {
          m2 = fmaxf(m1, om2); m1 = om1; i1 = oi1;
        } else {
          m2 = fmaxf(m2, om1);
        }
      }
      float z = 0.f;
#pragma unroll
      for (int nt = 0; nt < 20; ++nt) z += __expf(acc[mt][nt][reg] - m1);
#pragma unroll
      for (int off = 1; off <= 8; off <<= 1) z += __shfl_xor(z, off);
      float rz = 1.f / z;
#pragma unroll
      for (int nt = 0; nt < 20; ++nt)
        pp[nt] += __expf(acc[mt][nt][reg] - m1) * rz;

      if (l15 == 0) {
        int glocal = rbase + mt * 16 + quad * 4 + reg;
        int grow = row0 + glocal;
        rowk[glocal][g] = i1;
        k_idx[grow * 2 + g] = i1;
        atomicAdd(&hist[g * VDIM + i1], 1.f);
        if (m1 - m2 < TAU1) {
          int qi = atomicAdd(&qc[g], 1);
          if (qi < Q1CAP) qg[qi] = grow;
        }
      }
    }
  }
#pragma unroll
  for (int nt = 0; nt < 20; ++nt) {
    pp[nt] += __shfl_xor(pp[nt], 16);
    pp[nt] += __shfl_xor(pp[nt], 32);
  }
  if (quad == 0) {
    float* dst = ws_avgp + (size_t)(blockIdx.x & (NREP - 1)) * MDIM + g * VDIM + l15;
#pragma unroll
    for (int nt = 0; nt < 20; ++nt) atomicAdd(dst + nt * 16, pp[nt]);
  }

  // ---- fused gather-write: out rows from rowk ----
  __syncthreads();
  const float4* cb4 = (const float4*)cb;
  float4* out4 = (float4*)out;
#pragma unroll
  for (int it = 0; it < 16; ++it) {
    int i = it * 512 + t;         // 8192 float4 slots = 128 rows * 64
    int row = i >> 6, f4 = i & 63;
    int gg = f4 >> 5, d4 = f4 & 31;
    int kk = rowk[row][gg];
    out4[(size_t)(row0 + row) * 64 + f4] = cb4[(size_t)(gg * VDIM + kk) * 32 + d4];
  }
}

// ---- tier-2: f16x3 recompute of flagged entries; fix-forward out/hist ----
// NEW: 512 threads = 8 waves; waves 0-3 process g0 entries, waves 4-7 g1
// CONCURRENTLY (no sequential g loop). Both groups' W (hi+lo, 80KB) staged
// per ks into a single LDS buffer: threads 0-255 stage g0 planes, 256-511
// g1 planes (10 GLD16 each). Two raw barriers per ks, both with cheap
// drains (lgkmcnt(0) after reads; vmcnt(0) after stage, x-prefetch already
// landed). Doubles active CUs' concurrency and waves/SIMD vs old version.
__global__ __launch_bounds__(512) void t2_kernel(
    const float* __restrict__ x, const float* __restrict__ bias,
    const _Float16* __restrict__ wpk_hi, const _Float16* __restrict__ wpk_lo,
    const int* __restrict__ q1g0, const int* __restrict__ q1g1,
    const int* __restrict__ qc, int* __restrict__ k_idx,
    int* __restrict__ q2, int* __restrict__ qc2,
    const float* __restrict__ cb, float* __restrict__ out,
    float* __restrict__ hist) {
  __shared__ alignas(16) _Float16 whl[2][2][10240];  // [g][hi/lo][20KB] = 80KB
  __shared__ int sh_row[8][16];
  __shared__ int sh_k[8][16];
  const int t = threadIdx.x;
  const int wave = t >> 6, lane = t & 63;
  const int quad = lane >> 4, l15 = lane & 15;
  const int g = wave >> 2;        // waves 0-3 -> g0, 4-7 -> g1
  const int wg = wave & 3;        // entry sub-block within group
  const int tl = t & 255;         // staging lane
  const int gs = t >> 8;          // staging plane (threads 0-255: g0; rest g1)
  const float4* cb4 = (const float4*)cb;
  float4* out4 = (float4*)out;
  const float4* whi4 = (const float4*)wpk_hi;  // 1280 float4 per (ks,g) block
  const float4* wlo4 = (const float4*)wpk_lo;

  int n0 = qc[0]; if (n0 > Q1CAP) n0 = Q1CAP;
  int n1 = qc[1]; if (n1 > Q1CAP) n1 = Q1CAP;
  const int nmax = (n0 > n1) ? n0 : n1;
  const int myn = (g == 0) ? n0 : n1;
  const int* queue = (g == 0) ? q1g0 : q1g1;

  for (int tbase0 = blockIdx.x * 64; tbase0 < nmax; tbase0 += gridDim.x * 64) {
    int tbase = tbase0 + wg * 16;
    int e = tbase + l15;
    int row = (e < myn) ? queue[e] : 0;

    f32x4 acc[20];
#pragma unroll
    for (int nt = 0; nt < 20; ++nt) acc[nt] = (f32x4)0.f;

    const float4* xp = (const float4*)x + (size_t)row * 128 + quad * 2;

    // prologue: stage ks=0 (both g planes, 20 GLD16 total), prefetch x(0)
    {
      const float4* shp = whi4 + (size_t)(0 * 2 + gs) * 1280;
      const float4* slp = wlo4 + (size_t)(0 * 2 + gs) * 1280;
#pragma unroll
      for (int j = 0; j < 5; ++j) {
        GLD16(shp + j * 256 + tl, &whl[gs][0][(size_t)(j * 256 + tl) * 8]);
        GLD16(slp + j * 256 + tl, &whl[gs][1][(size_t)(j * 256 + tl) * 8]);
      }
    }
    SCHED_FENCE();
    float4 va = xp[0], vb = xp[1];
    SCHED_FENCE();
    asm volatile("s_waitcnt vmcnt(2)" ::: "memory");  // 10 GLD16 retired
    __builtin_amdgcn_s_barrier();

#pragma unroll 1
    for (int ks = 0; ks < 16; ++ks) {
      // convert x(ks) -> f16 hi/lo fragments
      half8 ah, al;
      {
        float vv[8] = {va.x, va.y, va.z, va.w, vb.x, vb.y, vb.z, vb.w};
#pragma unroll
        for (int j = 0; j < 8; ++j) {
          ah[j] = (_Float16)vv[j];
          al[j] = (_Float16)(vv[j] - (float)ah[j]);
        }
      }
      // prefetch x(ks+1) (in flight across MFMA + stage phases)
      if (ks < 15) {
        va = xp[(ks + 1) * 8];
        vb = xp[(ks + 1) * 8 + 1];
      }
      SCHED_FENCE();
#pragma unroll
      for (int nt = 0; nt < 20; ++nt) {
        half8 bh = *(const half8*)&whl[g][0][nt * 512 + lane * 8];
        half8 bl = *(const half8*)&whl[g][1][nt * 512 + lane * 8];
        acc[nt] = __builtin_amdgcn_mfma_f32_16x16x32_f16(ah, bh, acc[nt], 0, 0, 0);
        acc[nt] = __builtin_amdgcn_mfma_f32_16x16x32_f16(ah, bl, acc[nt], 0, 0, 0);
        acc[nt] = __builtin_amdgcn_mfma_f32_16x16x32_f16(al, bh, acc[nt], 0, 0, 0);
      }
      SCHED_FENCE();
      asm volatile("s_waitcnt lgkmcnt(0)" ::: "memory");  // LDS reads retired
      SCHED_FENCE();
      __builtin_amdgcn_s_barrier();  // all waves done reading buf(ks)
      if (ks < 15) {
        const float4* shp = whi4 + (size_t)((ks + 1) * 2 + gs) * 1280;
        const float4* slp = wlo4 + (size_t)((ks + 1) * 2 + gs) * 1280;
#pragma unroll
        for (int j = 0; j < 5; ++j) {
          GLD16(shp + j * 256 + tl, &whl[gs][0][(size_t)(j * 256 + tl) * 8]);
          GLD16(slp + j * 256 + tl, &whl[gs][1][(size_t)(j * 256 + tl) * 8]);
        }
        SCHED_FENCE();
        // drains GLD16(ks+1); x(ks+1) is older and long since landed
        asm volatile("s_waitcnt vmcnt(0)" ::: "memory");
        __builtin_amdgcn_s_barrier();  // stage(ks+1) visible to all waves
      }
    }

#pragma unroll
    for (int reg = 0; reg < 4; ++reg) {
      float m1 = -1e30f, m2 = -1e30f;
      int i1 = 0;
#pragma unroll
      for (int nt = 0; nt < 20; ++nt) {
        float v = acc[nt][reg] + bias[g * VDIM + nt * 16 + l15];
        int ci = nt * 16 + l15;
        if (v > m1) { m2 = m1; m1 = v; i1 = ci; }
        else if (v > m2) m2 = v;
      }
#pragma unroll
      for (int off = 1; off <= 8; off <<= 1) {
        float om1 = __shfl_xor(m1, off);
        int oi1 = __shfl_xor(i1, off);
        float om2 = __shfl_xor(m2, off);
        if (om1 > m1 || (om1 == m1 && oi1 < i1)) {
          m2 = fmaxf(m1, om2); m1 = om1; i1 = oi1;
        } else {
          m2 = fmaxf(m2, om1);
        }
      }
      if (l15 == 0) {
        int ew = tbase + quad * 4 + reg;
        int ent = quad * 4 + reg;
        if (ew < myn) {
          int rw = queue[ew];
          int kold = k_idx[rw * 2 + g];
          if (i1 != kold) {
            atomicAdd(&hist[g * VDIM + kold], -1.f);
            atomicAdd(&hist[g * VDIM + i1], 1.f);
            k_idx[rw * 2 + g] = i1;
          }
          sh_row[wave][ent] = rw;
          sh_k[wave][ent] = i1;
          if (m1 - m2 < TAU2) {
            int qi = atomicAdd(qc2, 1);
            if (qi < Q2CAP) q2[qi] = rw * 2 + g;
          }
        } else {
          sh_row[wave][ent] = -1;
        }
      }
    }
    // wave-lockstep: LDS writes above visible to this wave's lanes
#pragma unroll
    for (int j = 0; j < 8; ++j) {
      int slot = j * 64 + lane;     // 512 slots = 16 ents * 32 float4
      int ent = slot >> 5, d4 = slot & 31;
      int rr = sh_row[wave][ent];
      if (rr >= 0) {
        int kk = sh_k[wave][ent];
        out4[(size_t)rr * 64 + g * 32 + d4] = cb4[(size_t)(g * VDIM + kk) * 32 + d4];
      }
    }
  }
}

// ---- tier-3: exact f64 recompute; fix-forward out/hist ----
__global__ __launch_bounds__(256) void fixup_kernel(
    const float* __restrict__ x, const float* __restrict__ W,
    const float* __restrict__ bias, const int* __restrict__ queue,
    const int* __restrict__ qcount, const int* __restrict__ k_idx,
    const float* __restrict__ cb, float* __restrict__ out,
    float* __restrict__ hist) {
  __shared__ float xrow[CDIM];
  __shared__ double sval[256];
  __shared__ int sidx[256];
  __shared__ int sk3;
  const int t = threadIdx.x;
  int n = *qcount;
  if (n > Q2CAP) n = Q2CAP;
  for (int i = blockIdx.x; i < n; i += gridDim.x) {
    int e = queue[i];
    int row = e >> 1, g = e & 1;
    __syncthreads();
    xrow[t] = x[(size_t)row * CDIM + t];
    xrow[t + 256] = x[(size_t)row * CDIM + 256 + t];
    __syncthreads();
    double bv = -1e300;
    int bi = 0;
    for (int c = t; c < VDIM; c += 256) {
      const float* wp = W + g * VDIM + c;
      double a0 = 0, a1 = 0, a2 = 0, a3 = 0;
      for (int k = 0; k < CDIM; k += 4) {
        a0 = fma((double)xrow[k],     (double)wp[(size_t)k * MDIM], a0);
        a1 = fma((double)xrow[k + 1], (double)wp[(size_t)(k + 1) * MDIM], a1);
        a2 = fma((double)xrow[k + 2], (double)wp[(size_t)(k + 2) * MDIM], a2);
        a3 = fma((double)xrow[k + 3], (double)wp[(size_t)(k + 3) * MDIM], a3);
      }
      double a = ((a0 + a1) + (a2 + a3)) + (double)bias[g * VDIM + c];
      if (a > bv) { bv = a; bi = c; }
    }
    sval[t] = bv; sidx[t] = bi;
    __syncthreads();
    for (int s = 128; s > 0; s >>= 1) {
      if (t < s) {
        if (sval[t + s] > sval[t] ||
            (sval[t + s] == sval[t] && sidx[t + s] < sidx[t])) {
          sval[t] = sval[t + s]; sidx[t] = sidx[t + s];
        }
      }
      __syncthreads();
    }
    if (t == 0) {
      int k3 = sidx[0];
      int kold = k_idx[row * 2 + g];
      if (k3 != kold) {
        atomicAdd(&hist[g * VDIM + kold], -1.f);
        atomicAdd(&hist[g * VDIM + k3], 1.f);
      }
      sk3 = k3;
    }
    __syncthreads();
    if (t < 32) {
      const float4* cb4 = (const float4*)cb;
      float4* out4 = (float4*)out;
      out4[(size_t)row * 64 + g * 32 + t] = cb4[(size_t)(g * VDIM + sk3) * 32 + t];
    }
  }
}

__global__ __launch_bounds__(256) void gvq_finalize_kernel(
    const float* __restrict__ ws_avgp, const float* __restrict__ ws_hist,
    float* __restrict__ out) {
  __shared__ double red[256];
  const int t = threadIdx.x;
  double pp[2] = {0.0, 0.0}, hp[2] = {0.0, 0.0};
  for (int c = t; c < MDIM; c += 256) {
    double s = 0.0;
    for (int rep = 0; rep < NREP; ++rep) s += (double)ws_avgp[rep * MDIM + c];
    double avg = s / (double)NROWS;
    double hard = (double)ws_hist[c] / (double)NROWS;
    int g = (c < VDIM) ? 0 : 1;
    pp[g] += avg * log(avg + 1e-7);
    hp[g] += hard * log(hard + 1e-7);
  }
  double vals[4] = {pp[0], pp[1], hp[0], hp[1]};
  double res[4];
  for (int i = 0; i < 4; ++i) {
    red[t] = vals[i];
    __syncthreads();
    for (int s = 128; s > 0; s >>= 1) {
      if (t < s) red[t] += red[t + s];
      __syncthreads();
    }
    res[i] = red[0];
    __syncthreads();
  }
  if (t == 0) {
    out[OUTN]     = (float)(exp(-res[2]) + exp(-res[3]));
    out[OUTN + 1] = (float)(exp(-res[0]) + exp(-res[1]));
  }
}

// ================= fallback (round-1 verified f64 path) =================
__global__ __launch_bounds__(256) void zero_ws_kernel(float* ws, int n) {
  int i = blockIdx.x * 256 + threadIdx.x;
  if (i < n) ws[i] = 0.f;
}

__global__ __launch_bounds__(256) void fb_main_kernel(
    const float* __restrict__ x, const float* __restrict__ W,
    const float* __restrict__ b, const float* __restrict__ cb,
    float* __restrict__ out, float* __restrict__ ws_avgp,
    float* __restrict__ ws_hist) {
  __shared__ float xs[8][CDIM];
  __shared__ float lg[8][MDIM];
  __shared__ float avgp[MDIM];
  __shared__ int rowk[8][2];
  const int t = threadIdx.x;
  const int row0 = blockIdx.x * 8;
  avgp[t] = 0.f; avgp[t + 256] = 0.f;
  if (t < 128) avgp[t + 512] = 0.f;
  const float4* x4 = (const float4*)(x + (size_t)row0 * CDIM);
  float4* xs4 = (float4*)&xs[0][0];
#pragma unroll
  for (int i = 0; i < 4; ++i) xs4[t + i * 256] = x4[t + i * 256];
  __syncthreads();
  const int c0 = t, c1 = t + 256;
  const int c2 = (t < 128) ? (t + 512) : 639;
  double a0[8], a1[8], a2[8];
#pragma unroll
  for (int r = 0; r < 8; ++r) { a0[r] = 0.0; a1[r] = 0.0; a2[r] = 0.0; }
  const float* Wk = W;
  for (int k = 0; k < CDIM; ++k) {
    double w0 = (double)Wk[c0], w1 = (double)Wk[c1], w2 = (double)Wk[c2];
#pragma unroll
    for (int r = 0; r < 8; ++r) {
      double xv = (double)xs[r][k];
      a0[r] = fma(xv, w0, a0[r]);
      a1[r] = fma(xv, w1, a1[r]);
      a2[r] = fma(xv, w2, a2[r]);
    }
    Wk += MDIM;
  }
#pragma unroll
  for (int r = 0; r < 8; ++r) {
    lg[r][c0] = (float)(a0[r] + (double)b[c0]);
    lg[r][c1] = (float)(a1[r] + (double)b[c1]);
    if (t < 128) lg[r][c2] = (float)(a2[r] + (double)b[c2]);
  }
  __syncthreads();
  const int wave = t >> 6, lane = t & 63;
  for (int r = wave; r < 8; r += 4) {
    float m0 = -1e30f, m1 = -1e30f;
    int i0 = 0, i1 = VDIM;
    float e0v[5], e1v[5];
#pragma unroll
    for (int j = 0; j < 5; ++j) {
      int ca = lane + j * 64;
      float v = lg[r][ca]; e0v[j] = v;
      if (v > m0) { m0 = v; i0 = ca; }
      float v2 = lg[r][VDIM + ca]; e1v[j] = v2;
      if (v2 > m1) { m1 = v2; i1 = VDIM + ca; }
    }
#pragma unroll
    for (int off = 32; off > 0; off >>= 1) {
      float om = __shfl_xor(m0, off); int oi = __shfl_xor(i0, off);
      if (om > m0 || (om == m0 && oi < i0)) { m0 = om; i0 = oi; }
      om = __shfl_xor(m1, off); oi = __shfl_xor(i1, off);
      if (om > m1 || (om == m1 && oi < i1)) { m1 = om; i1 = oi; }
    }
    float z0 = 0.f, z1 = 0.f;
#pragma unroll
    for (int j = 0; j < 5; ++j) {
      e0v[j] = expf(e0v[j] - m0); z0 += e0v[j];
      e1v[j] = expf(e1v[j] - m1); z1 += e1v[j];
    }
#pragma unroll
    for (int off = 32; off > 0; off >>= 1) {
      z0 += __shfl_xor(z0, off); z1 += __shfl_xor(z1, off);
    }
    float r0 = 1.f / z0, r1 = 1.f / z1;
#pragma unroll
    for (int j = 0; j < 5; ++j) {
      atomicAdd(&avgp[lane + j * 64], e0v[j] * r0);
      atomicAdd(&avgp[VDIM + lane + j * 64], e1v[j] * r1);
    }
    if (lane == 0) {
      rowk[r][0] = i0; rowk[r][1] = i1 - VDIM;
      atomicAdd(&ws_hist[i0], 1.f);
      atomicAdd(&ws_hist[i1], 1.f);
    }
  }
  __syncthreads();
  const int g = t >> 7, dd = t & 127;
#pragma unroll
  for (int r = 0; r < 8; ++r) {
    int kk = rowk[r][g];
    out[(size_t)(row0 + r) * 256 + t] = cb[((size_t)(g * VDIM + kk)) * DDIM + dd];
  }
  float* dst = ws_avgp + (size_t)(blockIdx.x & 31) * MDIM;
  atomicAdd(&dst[t], avgp[t]);
  atomicAdd(&dst[t + 256], avgp[t + 256]);
  if (t < 128) atomicAdd(&dst[t + 512], avgp[t + 512]);
}

extern "C" void kernel_launch(void* const* d_in, const int* in_sizes, int n_in,
                              void* d_out, int out_size, void* d_ws, size_t ws_size,
                              hipStream_t stream) {
  const float* x  = (const float*)d_in[0];
  const float* W  = (const float*)d_in[1];
  const float* b  = (const float*)d_in[2];
  const float* cb = (const float*)d_in[3];
  float* out = (float*)d_out;
  char* ws = (char*)d_ws;

  if (ws_size >= (size_t)WS_NEEDED) {
    _Float16* wpk_hi = (_Float16*)(ws + WPK_HI_OFF);
    _Float16* wpk_lo = (_Float16*)(ws + WPK_LO_OFF);
    int* k_idx = (int*)(ws + KIDX_OFF);
    int* q1g0 = (int*)(ws + Q1G0_OFF);
    int* q1g1 = (int*)(ws + Q1G1_OFF);
    int* q2   = (int*)(ws + Q2_OFF);
    int* qc   = (int*)(ws + CNT_OFF);
    float* avgp = (float*)(ws + AVGP_OFF);
    float* hist = (float*)(ws + HIST_OFF);

    prep_kernel<<<160 + ZBLOCKS, 256, 0, stream>>>(W, wpk_hi, wpk_lo,
                                                   (float*)(ws + CNT_OFF));
    t1_gemm_kernel<<<NROWS / 128, 512, 0, stream>>>(x, b, wpk_hi, cb, out,
                                                    k_idx, q1g0, q1g1, qc,
                                                    avgp, hist);
    t2_kernel<<<128, 512, 0, stream>>>(x, b, wpk_hi, wpk_lo, q1g0, q1g1, qc,
                                       k_idx, q2, qc + 2, cb, out, hist);
    fixup_kernel<<<128, 256, 0, stream>>>(x, W, b, q2, qc + 2, k_idx, cb, out,
                                          hist);
    gvq_finalize_kernel<<<1, 256, 0, stream>>>(avgp, hist, out);
  } else {
    float* ws_avgp = (float*)ws;
    float* ws_hist = (float*)ws + NREP * MDIM;
    const int zn = NREP * MDIM + MDIM;
    zero_ws_kernel<<<(zn + 255) / 256, 256, 0, stream>>>((float*)ws, zn);
    fb_main_kernel<<<NROWS / 8, 256, 0, stream>>>(x, W, b, cb, out, ws_avgp, ws_hist);
    gvq_finalize_kernel<<<1, 256, 0, stream>>>(ws_avgp, ws_hist, out);
  }
}